// Round 1
// baseline (133.888 us; speedup 1.0000x reference)
//
#include <hip/hip_runtime.h>

// Problem constants
#define BB 16
#define NN 256
#define NH 8
#define HID 64
#define NIN 12
#define NPAIRS (BB * NN * NN)   // 1048576
#define PPT 4                   // pairs per thread
#define BLOCK 256

__global__ __launch_bounds__(BLOCK) void relfeat_mlp_kernel(
    const float* __restrict__ ff,   // (B,N,N,4)
    const float* __restrict__ W1,   // (12,64)
    const float* __restrict__ b1,   // (64)
    const float* __restrict__ W2,   // (64,8)
    const float* __restrict__ b2,   // (8)
    float* __restrict__ out)        // (B,8,N,N)
{
    // Stage weights in LDS. W1 transposed to [h][f] so each hidden unit's
    // 12-float row is contiguous (48B, 16B-aligned -> ds_read_b128 x3).
    __shared__ float sW1t[HID * NIN];  // [h][f]
    __shared__ float sW2[HID * NH];    // [h][o], 32B rows
    __shared__ float sB1[HID];
    __shared__ float sB2[NH];

    const int tid = threadIdx.x;
    for (int i = tid; i < HID * NIN; i += BLOCK) {
        int h = i / NIN, f = i - h * NIN;
        sW1t[i] = W1[f * HID + h];
    }
    for (int i = tid; i < HID * NH; i += BLOCK) sW2[i] = W2[i];
    if (tid < HID) sB1[tid] = b1[tid];
    if (tid < NH)  sB2[tid] = b2[tid];
    __syncthreads();

    const long base = (long)blockIdx.x * (BLOCK * PPT);

    float feats[PPT][NIN];
    float oacc[PPT][NH];

    #pragma unroll
    for (int k = 0; k < PPT; ++k) {
        long p = base + (long)k * BLOCK + tid;      // lane-contiguous
        float4 v = ((const float4*)ff)[p];
        float rx = v.x, ry = v.y, rvx = v.z, rvy = v.w;

        float dist_sq = rx * rx + ry * ry;
        float dist = sqrtf(dist_sq + 1e-6f);
        float inv_dist = __builtin_amdgcn_rcpf(dist + 0.1f);
        float invd = __builtin_amdgcn_rcpf(dist + 1e-6f);
        float dir_x = rx * invd, dir_y = ry * invd;
        float speed_sq = rvx * rvx + rvy * rvy;
        float rel_speed = sqrtf(speed_sq + 1e-6f);
        float dot_vp = rvx * rx + rvy * ry;
        float closing = dot_vp * invd;
        float ttca = tanhf(-dot_vp * __builtin_amdgcn_rcpf(speed_sq + 1e-6f));

        feats[k][0] = rx;       feats[k][1] = ry;
        feats[k][2] = rvx;      feats[k][3] = rvy;
        feats[k][4] = dist;     feats[k][5] = inv_dist;
        feats[k][6] = rel_speed;feats[k][7] = closing;
        feats[k][8] = dir_x;    feats[k][9] = dir_y;
        feats[k][10] = ttca;    feats[k][11] = dot_vp;

        #pragma unroll
        for (int o = 0; o < NH; ++o) oacc[k][o] = sB2[o];
    }

    // Hidden-unit loop: load each unit's weights ONCE, reuse across PPT pairs.
    for (int h = 0; h < HID; ++h) {
        float w1r[NIN];
        #pragma unroll
        for (int f = 0; f < NIN; ++f) w1r[f] = sW1t[h * NIN + f];
        float b1h = sB1[h];
        float w2r[NH];
        #pragma unroll
        for (int o = 0; o < NH; ++o) w2r[o] = sW2[h * NH + o];

        #pragma unroll
        for (int k = 0; k < PPT; ++k) {
            float acc = b1h;
            #pragma unroll
            for (int f = 0; f < NIN; ++f) acc += feats[k][f] * w1r[f];
            // silu(x) = x / (1 + exp(-x)); v_exp/v_rcp fast path
            float s = acc * __builtin_amdgcn_rcpf(1.0f + __expf(-acc));
            #pragma unroll
            for (int o = 0; o < NH; ++o) oacc[k][o] += s * w2r[o];
        }
    }

    // Store: out[b][o][n][m]; p = b*65536 + (n*256+m)
    #pragma unroll
    for (int k = 0; k < PPT; ++k) {
        long p = base + (long)k * BLOCK + tid;
        long b = p >> 16;
        long lo = p & 65535;
        float* op = out + b * (long)(NH * NN * NN) + lo;
        #pragma unroll
        for (int o = 0; o < NH; ++o) op[(long)o * (NN * NN)] = oacc[k][o];
    }
}

extern "C" void kernel_launch(void* const* d_in, const int* in_sizes, int n_in,
                              void* d_out, int out_size, void* d_ws, size_t ws_size,
                              hipStream_t stream) {
    const float* ff = (const float*)d_in[0];
    const float* W1 = (const float*)d_in[1];
    const float* b1 = (const float*)d_in[2];
    const float* W2 = (const float*)d_in[3];
    const float* b2 = (const float*)d_in[4];
    float* out = (float*)d_out;

    const int grid = NPAIRS / (BLOCK * PPT);  // 1024
    relfeat_mlp_kernel<<<grid, BLOCK, 0, stream>>>(ff, W1, b1, W2, b2, out);
}

// Round 2
// 113.051 us; speedup vs baseline: 1.1843x; 1.1843x over previous
//
#include <hip/hip_runtime.h>

#define BB 16
#define NN 256
#define NH 8
#define HID 64
#define NIN 12
#define NPAIRS (BB * NN * NN)   // 1048576
#define PPT 2                   // pairs per thread (one packed duo)
#define BLOCK 256
#define WREC 24                 // floats per packed weight record: 12 W1 + 1 b1 + 8 W2 + 3 pad

typedef float v2f __attribute__((ext_vector_type(2)));

// Pack weights into d_ws: for each hidden unit h, a 96B record:
//   [ W1[0..11][h], b1[h], W2[h][0..7], pad x3 ]
// Runs every call (d_ws is re-poisoned before each timed launch).
__global__ void pack_weights_kernel(const float* __restrict__ W1,
                                    const float* __restrict__ b1,
                                    const float* __restrict__ W2,
                                    float* __restrict__ wpk) {
    int h = threadIdx.x;
    if (h < HID) {
        float* r = wpk + h * WREC;
        #pragma unroll
        for (int f = 0; f < NIN; ++f) r[f] = W1[f * HID + h];
        r[NIN] = b1[h];
        #pragma unroll
        for (int o = 0; o < NH; ++o) r[NIN + 1 + o] = W2[h * NH + o];
        r[21] = 0.f; r[22] = 0.f; r[23] = 0.f;
    }
}

__global__ __launch_bounds__(BLOCK) void relfeat_mlp_kernel(
    const float* __restrict__ ff,    // (B,N,N,4)
    const float* __restrict__ wpk,   // packed weights, 64 x 24 floats (uniform -> SGPR)
    const float* __restrict__ b2,    // (8)
    float* __restrict__ out)         // (B,8,N,N)
{
    const int tid = threadIdx.x;
    const int base = blockIdx.x * (BLOCK * PPT);

    // ---- features for the duo (pair A = base+tid, pair B = base+256+tid) ----
    v2f feats2[NIN];
    {
        float4 va = ((const float4*)ff)[base + tid];
        float4 vb = ((const float4*)ff)[base + BLOCK + tid];
        float rxs[2]  = {va.x, vb.x};
        float rys[2]  = {va.y, vb.y};
        float rvxs[2] = {va.z, vb.z};
        float rvys[2] = {va.w, vb.w};
        #pragma unroll
        for (int d = 0; d < 2; ++d) {
            float rx = rxs[d], ry = rys[d], rvx = rvxs[d], rvy = rvys[d];
            float dist_sq = rx * rx + ry * ry;
            float dist = sqrtf(dist_sq + 1e-6f);
            float inv_dist = __builtin_amdgcn_rcpf(dist + 0.1f);
            float invd = __builtin_amdgcn_rcpf(dist + 1e-6f);
            float dir_x = rx * invd, dir_y = ry * invd;
            float speed_sq = rvx * rvx + rvy * rvy;
            float rel_speed = sqrtf(speed_sq + 1e-6f);
            float dot_vp = rvx * rx + rvy * ry;
            float closing = dot_vp * invd;
            float ttca = tanhf(-dot_vp * __builtin_amdgcn_rcpf(speed_sq + 1e-6f));
            feats2[0][d] = rx;        feats2[1][d] = ry;
            feats2[2][d] = rvx;       feats2[3][d] = rvy;
            feats2[4][d] = dist;      feats2[5][d] = inv_dist;
            feats2[6][d] = rel_speed; feats2[7][d] = closing;
            feats2[8][d] = dir_x;     feats2[9][d] = dir_y;
            feats2[10][d] = ttca;     feats2[11][d] = dot_vp;
        }
    }

    // ---- output accumulators, init with b2 (uniform loads -> SGPR splat) ----
    v2f o2[NH];
    #pragma unroll
    for (int o = 0; o < NH; ++o) {
        float b = b2[o];
        o2[o] = (v2f){b, b};
    }

    // ---- hidden-unit loop: all weights via uniform s_load, math via v_pk_fma_f32 ----
    #pragma unroll 2
    for (int h = 0; h < HID; ++h) {
        const float* wp = wpk + h * WREC;
        float b1h = wp[NIN];
        v2f acc = (v2f){b1h, b1h};
        #pragma unroll
        for (int f = 0; f < NIN; ++f) {
            float w = wp[f];
            acc = __builtin_elementwise_fma(feats2[f], (v2f){w, w}, acc);
        }
        // silu(x) = x * 1/(1+exp(-x))
        v2f e;
        e[0] = __expf(-acc[0]);
        e[1] = __expf(-acc[1]);
        v2f den = e + (v2f){1.0f, 1.0f};
        v2f r;
        r[0] = __builtin_amdgcn_rcpf(den[0]);
        r[1] = __builtin_amdgcn_rcpf(den[1]);
        v2f s = acc * r;
        #pragma unroll
        for (int o = 0; o < NH; ++o) {
            float w = wp[NIN + 1 + o];
            o2[o] = __builtin_elementwise_fma(s, (v2f){w, w}, o2[o]);
        }
    }

    // ---- stores: out[b][o][n*256+m], p = b*65536 + lo ----
    #pragma unroll
    for (int k = 0; k < PPT; ++k) {
        int p = base + k * BLOCK + tid;
        int b = p >> 16;
        int lo = p & 65535;
        float* op = out + (long)b * (NH * NN * NN) + lo;
        #pragma unroll
        for (int o = 0; o < NH; ++o) op[o * (NN * NN)] = o2[o][k];
    }
}

extern "C" void kernel_launch(void* const* d_in, const int* in_sizes, int n_in,
                              void* d_out, int out_size, void* d_ws, size_t ws_size,
                              hipStream_t stream) {
    const float* ff = (const float*)d_in[0];
    const float* W1 = (const float*)d_in[1];
    const float* b1 = (const float*)d_in[2];
    const float* W2 = (const float*)d_in[3];
    const float* b2 = (const float*)d_in[4];
    float* out = (float*)d_out;
    float* wpk = (float*)d_ws;   // 64 * 24 * 4 = 6144 bytes

    pack_weights_kernel<<<1, 64, 0, stream>>>(W1, b1, W2, wpk);
    const int grid = NPAIRS / (BLOCK * PPT);  // 2048
    relfeat_mlp_kernel<<<grid, BLOCK, 0, stream>>>(ff, wpk, b2, out);
}

// Round 3
// 112.284 us; speedup vs baseline: 1.1924x; 1.0068x over previous
//
#include <hip/hip_runtime.h>

#define BB 16
#define NN 256
#define NH 8
#define HID 64
#define NIN 12
#define NPAIRS (BB * NN * NN)   // 1048576
#define PPT 4                   // pairs per thread = 2 packed duos
#define BLOCK 256
#define WREC 24                 // packed record: 12 W1 + 1 b1 + 8 W2 + 3 pad

typedef float v2f __attribute__((ext_vector_type(2)));

// Pack weights into d_ws: per hidden unit h, a 96B record:
//   [ W1[0..11][h], b1[h], W2[h][0..7], pad x3 ]
__global__ void pack_weights_kernel(const float* __restrict__ W1,
                                    const float* __restrict__ b1,
                                    const float* __restrict__ W2,
                                    float* __restrict__ wpk) {
    int h = threadIdx.x;
    if (h < HID) {
        float* r = wpk + h * WREC;
        #pragma unroll
        for (int f = 0; f < NIN; ++f) r[f] = W1[f * HID + h];
        r[NIN] = b1[h];
        #pragma unroll
        for (int o = 0; o < NH; ++o) r[NIN + 1 + o] = W2[h * NH + o];
        r[21] = 0.f; r[22] = 0.f; r[23] = 0.f;
    }
}

__global__ __launch_bounds__(BLOCK) void relfeat_mlp_kernel(
    const float* __restrict__ ff,    // (B,N,N,4)
    const float* __restrict__ wpk,   // packed weights (uniform -> SGPR)
    const float* __restrict__ b2,    // (8)
    float* __restrict__ out)         // (B,8,N,N)
{
    const int tid = threadIdx.x;
    const int base = blockIdx.x * (BLOCK * PPT);

    // ---- features: 2 duos; duo d = pairs (base + (2d)*256 + tid, base + (2d+1)*256 + tid)
    v2f feats2[2][NIN];
    #pragma unroll
    for (int d = 0; d < 2; ++d) {
        float4 va = ((const float4*)ff)[base + (2 * d) * BLOCK + tid];
        float4 vb = ((const float4*)ff)[base + (2 * d + 1) * BLOCK + tid];
        float rxs[2]  = {va.x, vb.x};
        float rys[2]  = {va.y, vb.y};
        float rvxs[2] = {va.z, vb.z};
        float rvys[2] = {va.w, vb.w};
        #pragma unroll
        for (int e = 0; e < 2; ++e) {
            float rx = rxs[e], ry = rys[e], rvx = rvxs[e], rvy = rvys[e];
            float dist_sq = rx * rx + ry * ry;
            float dist = sqrtf(dist_sq + 1e-6f);
            float inv_dist = __builtin_amdgcn_rcpf(dist + 0.1f);
            float invd = __builtin_amdgcn_rcpf(dist + 1e-6f);
            float dir_x = rx * invd, dir_y = ry * invd;
            float speed_sq = rvx * rvx + rvy * rvy;
            float rel_speed = sqrtf(speed_sq + 1e-6f);
            float dot_vp = rvx * rx + rvy * ry;
            float closing = dot_vp * invd;
            // tanh(z) = 1 - 2/(exp(2z)+1)  (1 exp + 1 rcp; exact at +-inf)
            float z = -dot_vp * __builtin_amdgcn_rcpf(speed_sq + 1e-6f);
            float ez = __expf(2.0f * z);
            float ttca = 1.0f - 2.0f * __builtin_amdgcn_rcpf(ez + 1.0f);
            feats2[d][0][e] = rx;        feats2[d][1][e] = ry;
            feats2[d][2][e] = rvx;       feats2[d][3][e] = rvy;
            feats2[d][4][e] = dist;      feats2[d][5][e] = inv_dist;
            feats2[d][6][e] = rel_speed; feats2[d][7][e] = closing;
            feats2[d][8][e] = dir_x;     feats2[d][9][e] = dir_y;
            feats2[d][10][e] = ttca;     feats2[d][11][e] = dot_vp;
        }
    }

    // ---- accumulators
    v2f o2[2][NH];
    #pragma unroll
    for (int o = 0; o < NH; ++o) {
        float b = b2[o];
        o2[0][o] = (v2f){b, b};
        o2[1][o] = (v2f){b, b};
    }

    // ---- hidden loop: each SGPR weight feeds 2 pk_fma (4 pairs)
    #pragma unroll 2
    for (int h = 0; h < HID; ++h) {
        const float* wp = wpk + h * WREC;
        float b1h = wp[NIN];
        v2f acc0 = (v2f){b1h, b1h};
        v2f acc1 = acc0;
        #pragma unroll
        for (int f = 0; f < NIN; ++f) {
            float w = wp[f];
            acc0 = __builtin_elementwise_fma(feats2[0][f], (v2f){w, w}, acc0);
            acc1 = __builtin_elementwise_fma(feats2[1][f], (v2f){w, w}, acc1);
        }
        // silu(x) = x * rcp(1 + exp(-x))
        v2f s0, s1;
        #pragma unroll
        for (int e = 0; e < 2; ++e) {
            s0[e] = acc0[e] * __builtin_amdgcn_rcpf(1.0f + __expf(-acc0[e]));
            s1[e] = acc1[e] * __builtin_amdgcn_rcpf(1.0f + __expf(-acc1[e]));
        }
        #pragma unroll
        for (int o = 0; o < NH; ++o) {
            float w = wp[NIN + 1 + o];
            o2[0][o] = __builtin_elementwise_fma(s0, (v2f){w, w}, o2[0][o]);
            o2[1][o] = __builtin_elementwise_fma(s1, (v2f){w, w}, o2[1][o]);
        }
    }

    // ---- stores: pair p = base + k*256 + tid, k = 2d+e
    #pragma unroll
    for (int k = 0; k < PPT; ++k) {
        int p = base + k * BLOCK + tid;
        int b = p >> 16;
        int lo = p & 65535;
        float* op = out + (long)b * (NH * NN * NN) + lo;
        #pragma unroll
        for (int o = 0; o < NH; ++o) op[o * (NN * NN)] = o2[k >> 1][o][k & 1];
    }
}

extern "C" void kernel_launch(void* const* d_in, const int* in_sizes, int n_in,
                              void* d_out, int out_size, void* d_ws, size_t ws_size,
                              hipStream_t stream) {
    const float* ff = (const float*)d_in[0];
    const float* W1 = (const float*)d_in[1];
    const float* b1 = (const float*)d_in[2];
    const float* W2 = (const float*)d_in[3];
    const float* b2 = (const float*)d_in[4];
    float* out = (float*)d_out;
    float* wpk = (float*)d_ws;   // 64 * 24 * 4 = 6144 bytes

    pack_weights_kernel<<<1, 64, 0, stream>>>(W1, b1, W2, wpk);
    const int grid = NPAIRS / (BLOCK * PPT);  // 1024
    relfeat_mlp_kernel<<<grid, BLOCK, 0, stream>>>(ff, wpk, b2, out);
}